// Round 10
// baseline (223.280 us; speedup 1.0000x reference)
//
#include <hip/hip_runtime.h>
#include <hip/hip_bf16.h>

// Problem constants (CeptaBlock): B=4,T=2048,D=2048,P=512,K=16,ALPHA=4,R=32
#define B_ 4
#define T_ 2048
#define D_ 2048
#define P_ 512
#define K_ 16
#define ALPHA_ 4
#define R_ 32
#define NE_ 409        // int(0.8*512) -> excitatory count
#define EPS_ 1e-6f
#define G_ 4           // tokens per block

typedef unsigned short u16;
typedef unsigned int u32;
typedef _Float16 h2t __attribute__((ext_vector_type(2)));

__device__ __forceinline__ float sigmoidf_(float x) {
  return 1.0f / (1.0f + __expf(-x));
}
// f16 pair pack (v_cvt_pkrtz_f16_f32) and f16x2 weight duplication
__device__ __forceinline__ u32 packh(float lo, float hi) {
#if __has_builtin(__builtin_amdgcn_cvt_pkrtz)
  return __builtin_bit_cast(u32, __builtin_amdgcn_cvt_pkrtz(lo, hi));
#else
  union { _Float16 h; u16 u; } a, b;
  a.h = (_Float16)lo; b.h = (_Float16)hi;
  return ((u32)b.u << 16) | a.u;
#endif
}
__device__ __forceinline__ float hlo(u32 u) { return (float)__builtin_bit_cast(h2t, u).x; }
__device__ __forceinline__ float hhi(u32 u) { return (float)__builtin_bit_cast(h2t, u).y; }
__device__ __forceinline__ u32 duph(float w) {
  union { _Float16 h; u16 u; } c;
  c.h = (_Float16)w;
  return ((u32)c.u << 16) | c.u;
}
// packed f16 fma: acc += h * w (both lanes) -> v_pk_fma_f16
__device__ __forceinline__ h2t pkfma(u32 h, u32 w, h2t acc) {
  return __builtin_bit_cast(h2t, h) * __builtin_bit_cast(h2t, w) + acc;
}

// ---------------- K0: quant-dale scalars + f16x2-duplicated weight tables ----------------
__global__ void k_scalars(const float* __restrict__ Wp_s, const float* __restrict__ Wo_s,
                          const float* __restrict__ Wp_m, const float* __restrict__ Wo_m,
                          const float* __restrict__ U, const float* __restrict__ Wgt,
                          const float* __restrict__ wg_s, const float* __restrict__ wg_m,
                          float* __restrict__ wq_s, float* __restrict__ fo_s,
                          float* __restrict__ wq_m, float* __restrict__ fo_m,
                          u32* __restrict__ Ud, u32* __restrict__ Wd,
                          u32* __restrict__ wgd_s, u32* __restrict__ wgd_m) {
  int p = blockIdx.x * blockDim.x + threadIdx.x;
  if (p >= P_) return;
  float sgn = (p < NE_) ? 1.0f : -1.0f;
  float a = 0, b = 0, c = 0, d = 0;
#pragma unroll
  for (int k = 0; k < K_; k++) {
    a += fabsf(Wp_s[p * K_ + k]);
    c += fabsf(Wp_m[p * K_ + k]);
  }
#pragma unroll
  for (int k = 0; k < ALPHA_; k++) {
    b += fabsf(Wo_s[p * ALPHA_ + k]);
    d += fabsf(Wo_m[p * ALPHA_ + k]);
  }
  wq_s[p] = sgn * a * (1.0f / K_);
  fo_s[p] = sgn * b * (1.0f / ALPHA_);
  wq_m[p] = sgn * c * (1.0f / K_);
  fo_m[p] = sgn * d * (1.0f / ALPHA_);
#pragma unroll
  for (int r = 0; r < R_; r++) {
    Ud[p * R_ + r] = duph(U[p * R_ + r]);
    Wd[p * R_ + r] = duph(Wgt[p * R_ + r]);
  }
#pragma unroll
  for (int k = 0; k < K_; k++) {
    wgd_s[p * K_ + k] = duph(wg_s[p * K_ + k]);
    wgd_m[p * K_ + k] = duph(wg_m[p * K_ + k]);
  }
}

// ---------------- K1: 512 threads; rmsnorm1 + gather + perceptron + z/lam ----------------
// launch_bounds(512,8): VGPR<=64 -> 4 blocks/CU (32 waves) preserved.
// idx/wq prefetched before stage A (latency hides under stage A + barrier drain).
// Stage C reads tp/fp as uint4 (32 LDS reads/thread, round-8-proven shape).
__global__ __launch_bounds__(512, 8) void k_phase1(
    const float* __restrict__ x, const float* __restrict__ g1,
    const int* __restrict__ idx, const u32* __restrict__ wgd,
    const u32* __restrict__ Ud, const u32* __restrict__ Wd,
    const float* __restrict__ bg, const float* __restrict__ wq,
    u32* __restrict__ f_ssm, float* __restrict__ z, float* __restrict__ lam) {
  __shared__ union SU {
    u32 h1p[2][D_];                                            // 16 KB (stages A,B)
    struct { float zp[G_][R_][8]; float lp[G_][R_][8]; } c;    // 8 KB (stage C)
  } su;
  __shared__ u32 tp[2][P_];        // 4 KB  f16x2 (t_tokA, t_tokB)
  __shared__ u32 fp[2][P_];        // 4 KB  f16x2 (f_tokA, f_tokB)
  __shared__ float red[G_][8];

  int tid = threadIdx.x;
  int token0 = blockIdx.x * G_;
  int b = token0 >> 11;
  int t0 = token0 & (T_ - 1);

  // ---- prefetch stage-B gather indices + quant scale (L2 latency overlaps stage A) ----
  union { int4 v[4]; int s[16]; } iu;
  {
    const int4* ip = reinterpret_cast<const int4*>(idx + tid * K_);
    iu.v[0] = ip[0]; iu.v[1] = ip[1]; iu.v[2] = ip[2]; iu.v[3] = ip[3];
  }
  float wqp = wq[tid];

  // ---- stage A: 4 elems/thread/token; packed f16 h1 + ss partials ----
  float gv[4];
  *reinterpret_cast<float4*>(gv) = *reinterpret_cast<const float4*>(g1 + tid * 4);
#pragma unroll
  for (int pr = 0; pr < 2; pr++) {
    int ta = 2 * pr, tb = ta + 1;
    float xv0[4], xv1[4];
    *reinterpret_cast<float4*>(xv0) =
        *reinterpret_cast<const float4*>(x + (size_t)(token0 + ta) * D_ + tid * 4);
    *reinterpret_cast<float4*>(xv1) =
        *reinterpret_cast<const float4*>(x + (size_t)(token0 + tb) * D_ + tid * 4);
    float ss0 = 0, ss1 = 0;
    u32 tmp[4];
#pragma unroll
    for (int i = 0; i < 4; i++) {
      ss0 += xv0[i] * xv0[i];
      ss1 += xv1[i] * xv1[i];
      tmp[i] = packh(xv0[i] * gv[i], xv1[i] * gv[i]);
    }
    *reinterpret_cast<uint4*>(&su.h1p[pr][tid * 4]) = *reinterpret_cast<const uint4*>(tmp);
#pragma unroll
    for (int off = 32; off; off >>= 1) {
      ss0 += __shfl_down(ss0, off);
      ss1 += __shfl_down(ss1, off);
    }
    if ((tid & 63) == 0) { red[ta][tid >> 6] = ss0; red[tb][tid >> 6] = ss1; }
  }
  __syncthreads();

  float inv[G_];
#pragma unroll
  for (int tok = 0; tok < G_; tok++) {
    float s = 0;
#pragma unroll
    for (int w = 0; w < 8; w++) s += red[tok][w];
    inv[tok] = rsqrtf(s * (1.0f / D_) + EPS_);
  }

  // ---- stage B: one neuron per thread (p = tid); pk_fma gather ----
  {
    int p = tid;
    union { uint4 v[4]; u32 s[16]; } wd;
    const uint4* wp = reinterpret_cast<const uint4*>(wgd + p * K_);
    wd.v[0] = wp[0]; wd.v[1] = wp[1]; wd.v[2] = wp[2]; wd.v[3] = wp[3];
#pragma unroll
    for (int pr = 0; pr < 2; pr++) {
      int ta = 2 * pr, tb = ta + 1;
      h2t acc = {(_Float16)0.0f, (_Float16)0.0f};
#pragma unroll
      for (int k = 0; k < K_; k++) acc = pkfma(su.h1p[pr][iu.s[k]], wd.s[k], acc);
      float u0 = wqp * inv[ta] * (float)acc.x, u1 = wqp * inv[tb] * (float)acc.y;
      float f0 = sigmoidf_(u0), f1 = sigmoidf_(u1);
      tp[pr][p] = packh(f0 * u0, f1 * u1);
      u32 fpk = packh(f0, f1);
      fp[pr][p] = fpk;
      // pair-packed f16 f_ssm: one u32 store per pair (was 2 u16)
      f_ssm[(size_t)(2 * blockIdx.x + pr) * P_ + p] = fpk;
    }
  }
  __syncthreads();

  // ---- stage C: z = t@U, lam_pre = f@Wgt via pk_fma; uint4 LDS reads ----
  int r = tid & 31, g = tid >> 5;  // 32 r x 16 p-groups of 32
  float zs[G_] = {0, 0, 0, 0}, ls[G_] = {0, 0, 0, 0};
  int pb = g * 32;
#pragma unroll
  for (int c = 0; c < 4; c++) {     // chunks of 8 p: f16 accum dumped to f32
    h2t z0 = {(_Float16)0.0f, (_Float16)0.0f}, z1 = z0, l0 = z0, l1 = z0;
#pragma unroll
    for (int q = 0; q < 2; q++) {
      int p = pb + c * 8 + q * 4;
      uint4 t0 = *reinterpret_cast<const uint4*>(&tp[0][p]);
      uint4 t1 = *reinterpret_cast<const uint4*>(&tp[1][p]);
      uint4 f0 = *reinterpret_cast<const uint4*>(&fp[0][p]);
      uint4 f1 = *reinterpret_cast<const uint4*>(&fp[1][p]);
      u32 u0 = Ud[(p + 0) * R_ + r], u1 = Ud[(p + 1) * R_ + r];
      u32 u2 = Ud[(p + 2) * R_ + r], u3 = Ud[(p + 3) * R_ + r];
      u32 w0 = Wd[(p + 0) * R_ + r], w1 = Wd[(p + 1) * R_ + r];
      u32 w2 = Wd[(p + 2) * R_ + r], w3 = Wd[(p + 3) * R_ + r];
      z0 = pkfma(t0.w, u3, pkfma(t0.z, u2, pkfma(t0.y, u1, pkfma(t0.x, u0, z0))));
      z1 = pkfma(t1.w, u3, pkfma(t1.z, u2, pkfma(t1.y, u1, pkfma(t1.x, u0, z1))));
      l0 = pkfma(f0.w, w3, pkfma(f0.z, w2, pkfma(f0.y, w1, pkfma(f0.x, w0, l0))));
      l1 = pkfma(f1.w, w3, pkfma(f1.z, w2, pkfma(f1.y, w1, pkfma(f1.x, w0, l1))));
    }
    zs[0] += (float)z0.x; zs[1] += (float)z0.y; zs[2] += (float)z1.x; zs[3] += (float)z1.y;
    ls[0] += (float)l0.x; ls[1] += (float)l0.y; ls[2] += (float)l1.x; ls[3] += (float)l1.y;
  }
#pragma unroll
  for (int tok = 0; tok < G_; tok++) {
    zs[tok] += __shfl_down(zs[tok], 32);   // combine the wave's two p-groups
    ls[tok] += __shfl_down(ls[tok], 32);
  }
  int wid = tid >> 6;
  if ((tid & 63) < 32) {
#pragma unroll
    for (int tok = 0; tok < G_; tok++) { su.c.zp[tok][r][wid] = zs[tok]; su.c.lp[tok][r][wid] = ls[tok]; }
  }
  __syncthreads();
  if (tid < R_) {
    float bgr = bg[tid];
    float z4[G_], l4[G_];
#pragma unroll
    for (int tok = 0; tok < G_; tok++) {
      float zz = 0, ll = 0;
#pragma unroll
      for (int w = 0; w < 8; w++) { zz += su.c.zp[tok][tid][w]; ll += su.c.lp[tok][tid][w]; }
      z4[tok] = zz;
      l4[tok] = sigmoidf_(ll + bgr);
    }
    size_t o = ((size_t)(b * R_ + tid)) * T_ + t0;
    *reinterpret_cast<float4*>(&z[o]) = *reinterpret_cast<const float4*>(z4);
    *reinterpret_cast<float4*>(&lam[o]) = *reinterpret_cast<const float4*>(l4);
  }
}

// ---------------- K2: parallel linear scan over T (one wave per (b,r)) ----------------
__global__ __launch_bounds__(64) void k_scan(
    const float* __restrict__ z, const float* __restrict__ lam,
    const float* __restrict__ state, float* __restrict__ S,
    float* __restrict__ out_state) {
  int br = blockIdx.x;     // b*R + r   (128 total)
  int lane = threadIdx.x;  // 64 lanes, 32 timesteps each
  const float* zr = z + (size_t)br * T_ + lane * 32;
  const float* lr = lam + (size_t)br * T_ + lane * 32;
  float zb[32], lb[32];
#pragma unroll
  for (int i = 0; i < 32; i += 4) {
    *reinterpret_cast<float4*>(&zb[i]) = *reinterpret_cast<const float4*>(&zr[i]);
    *reinterpret_cast<float4*>(&lb[i]) = *reinterpret_cast<const float4*>(&lr[i]);
  }
  float A = 1.0f, Z = 0.0f;
#pragma unroll
  for (int i = 0; i < 32; i++) { Z = lb[i] * Z + zb[i]; A *= lb[i]; }
  for (int off = 1; off < 64; off <<= 1) {
    float Ap = __shfl_up(A, off);
    float Zp = __shfl_up(Z, off);
    if (lane >= off) { Z = A * Zp + Z; A = A * Ap; }
  }
  float s0 = state[br];
  float Ae = __shfl_up(A, 1);
  float Ze = __shfl_up(Z, 1);
  float s = (lane == 0) ? s0 : (Ae * s0 + Ze);
  float sb[32];
#pragma unroll
  for (int i = 0; i < 32; i++) { s = lb[i] * s + zb[i]; sb[i] = s; }
  float* Sr = S + (size_t)br * T_ + lane * 32;
#pragma unroll
  for (int i = 0; i < 32; i += 4)
    *reinterpret_cast<float4*>(&Sr[i]) = *reinterpret_cast<const float4*>(&sb[i]);
  if (lane == 63) out_state[br] = s;  // new_state
}

// ---------------- K3: 512 threads; tilde=S@V, y_ssm, x_after, rmsnorm2, MLP, out ----------------
// idx + f_ssm pair-words prefetched before the Sl barrier. launch_bounds(512,8).
__global__ __launch_bounds__(512, 8) void k_phase3(
    const float* __restrict__ x, const float* __restrict__ g2,
    const int* __restrict__ idx, const u32* __restrict__ wgd,
    const float* __restrict__ V, const float* __restrict__ S,
    const u32* __restrict__ f_ssm, const float* __restrict__ fo_s,
    const float* __restrict__ wq_m, const float* __restrict__ fo_m,
    float* __restrict__ out) {
  __shared__ float Sl[G_][R_];      // 0.5 KB
  __shared__ u32 h2p[2][D_];        // 16 KB  pair-packed f16(xa*g2), inv deferred
  __shared__ float red[G_][8];

  int tid = threadIdx.x;
  int token0 = blockIdx.x * G_;
  int b = token0 >> 11;
  int t0 = token0 & (T_ - 1);
  int p = tid;

  // ---- prefetch MLP gather indices + f_ssm pair words (hide under Sl/tilde) ----
  union { int4 v[4]; int s[16]; } iu;
  {
    const int4* ip = reinterpret_cast<const int4*>(idx + p * K_);
    iu.v[0] = ip[0]; iu.v[1] = ip[1]; iu.v[2] = ip[2]; iu.v[3] = ip[3];
  }
  u32 fw[2];
#pragma unroll
  for (int pr = 0; pr < 2; pr++)
    fw[pr] = f_ssm[(size_t)(2 * blockIdx.x + pr) * P_ + p];

  if (tid < G_ * R_) {
    int tok = tid >> 5, r = tid & 31;
    Sl[tok][r] = S[((size_t)(b * R_ + r)) * T_ + t0 + tok];
  }
  __syncthreads();

  // ---- tilde = S @ V: one V column per thread ----
  float til[G_] = {0, 0, 0, 0};
#pragma unroll 4
  for (int r = 0; r < R_; r++) {
    float v = V[r * P_ + p];
#pragma unroll
    for (int tok = 0; tok < G_; tok++) til[tok] += Sl[tok][r] * v;
  }

  float fo = fo_s[p];
  float gv[4];
  *reinterpret_cast<float4*>(gv) = *reinterpret_cast<const float4*>(g2 + tid * 4);

  // ---- xa = x + y_ssm; ss partials; pair-packed f16 h2 write ----
  float xa[G_][4];
#pragma unroll
  for (int pr = 0; pr < 2; pr++) {
    int ta = 2 * pr, tb = ta + 1;
#pragma unroll
    for (int h = 0; h < 2; h++) {
      int tok = ta + h;
      float fv = h ? hhi(fw[pr]) : hlo(fw[pr]);
      float val = fv * til[tok] * fo;
      float xv[4];
      *reinterpret_cast<float4*>(xv) =
          *reinterpret_cast<const float4*>(x + (size_t)(token0 + tok) * D_ + tid * 4);
      float ss = 0;
#pragma unroll
      for (int a = 0; a < 4; a++) {
        float v = xv[a] + val;
        xa[tok][a] = v;
        ss += v * v;
      }
#pragma unroll
      for (int off = 32; off; off >>= 1) ss += __shfl_down(ss, off);
      if ((tid & 63) == 0) red[tok][tid >> 6] = ss;
    }
    u32 tmp[4];
#pragma unroll
    for (int i = 0; i < 4; i++)
      tmp[i] = packh(xa[ta][i] * gv[i], xa[tb][i] * gv[i]);
    *reinterpret_cast<uint4*>(&h2p[pr][tid * 4]) = *reinterpret_cast<const uint4*>(tmp);
  }
  __syncthreads();

  float invt[G_];
#pragma unroll
  for (int tok = 0; tok < G_; tok++) {
    float s = 0;
#pragma unroll
    for (int w = 0; w < 8; w++) s += red[tok][w];
    invt[tok] = rsqrtf(s * (1.0f / D_) + EPS_);
  }

  // ---- MLP gather: one neuron per thread, pk_fma over token pairs ----
  union { uint4 v[4]; u32 s[16]; } wd;
  {
    const uint4* wp = reinterpret_cast<const uint4*>(wgd + p * K_);
#pragma unroll
    for (int q = 0; q < 4; q++) wd.v[q] = wp[q];
  }
  float wqm = wq_m[p];
  float fom = fo_m[p];

#pragma unroll
  for (int pr = 0; pr < 2; pr++) {
    h2t acc = {(_Float16)0.0f, (_Float16)0.0f};
#pragma unroll
    for (int k = 0; k < K_; k++) acc = pkfma(h2p[pr][iu.s[k]], wd.s[k], acc);
#pragma unroll
    for (int h = 0; h < 2; h++) {
      int tok = 2 * pr + h;
      float a = h ? (float)acc.y : (float)acc.x;
      float u = wqm * invt[tok] * a;
      float f = sigmoidf_(u);
      float val = f * u * fom;
      float ov[4];
#pragma unroll
      for (int a2 = 0; a2 < 4; a2++) ov[a2] = xa[tok][a2] + val;
      *reinterpret_cast<float4*>(out + (size_t)(token0 + tok) * D_ + tid * 4) =
          *reinterpret_cast<const float4*>(ov);
    }
  }
}

// ---------------- host ----------------
extern "C" void kernel_launch(void* const* d_in, const int* in_sizes, int n_in,
                              void* d_out, int out_size, void* d_ws, size_t ws_size,
                              hipStream_t stream) {
  const float* x     = (const float*)d_in[0];
  const float* state = (const float*)d_in[1];
  const float* g1    = (const float*)d_in[2];
  const float* g2    = (const float*)d_in[3];
  const int*   idx_s = (const int*)d_in[4];
  const float* wg_s  = (const float*)d_in[5];
  const int*   idx_m = (const int*)d_in[6];
  const float* wg_m  = (const float*)d_in[7];
  const float* Wp_s  = (const float*)d_in[8];
  const float* Wo_s  = (const float*)d_in[9];
  const float* Wp_m  = (const float*)d_in[10];
  const float* Wo_m  = (const float*)d_in[11];
  const float* U     = (const float*)d_in[12];
  const float* V     = (const float*)d_in[13];
  const float* Wgt   = (const float*)d_in[14];
  const float* bg    = (const float*)d_in[15];
  float* out = (float*)d_out;

  char* ws = (char*)d_ws;
  float* wq_s = (float*)(ws + 0);          // 2 KB
  float* fo_s = (float*)(ws + 2048);
  float* wq_m = (float*)(ws + 4096);
  float* fo_m = (float*)(ws + 6144);
  u32* Ud     = (u32*)(ws + 8192);                     // 64 KB f16x2-dup U  [P][R]
  u32* Wd     = (u32*)(ws + 8192 + 65536);             // 64 KB f16x2-dup Wgt[P][R]
  u32* wgd_s  = (u32*)(ws + 8192 + 131072);            // 32 KB f16x2-dup wg_s
  u32* wgd_m  = (u32*)(ws + 8192 + 163840);            // 32 KB f16x2-dup wg_m
  size_t off = 8192 + 196608;
  u32* f_ssm = (u32*)(ws + off); off += (size_t)(B_ * T_ / 2) * P_ * 4;  // 8 MB pair-packed f16
  float* z   = (float*)(ws + off); off += (size_t)B_ * R_ * T_ * 4;      // 1 MB
  float* lam = (float*)(ws + off); off += (size_t)B_ * R_ * T_ * 4;      // 1 MB
  float* S   = (float*)(ws + off);                                       // 1 MB

  hipLaunchKernelGGL(k_scalars, dim3(2), dim3(256), 0, stream,
                     Wp_s, Wo_s, Wp_m, Wo_m, U, Wgt, wg_s, wg_m,
                     wq_s, fo_s, wq_m, fo_m, Ud, Wd, wgd_s, wgd_m);
  hipLaunchKernelGGL(k_phase1, dim3(B_ * T_ / G_), dim3(512), 0, stream,
                     x, g1, idx_s, wgd_s, Ud, Wd, bg, wq_s, f_ssm, z, lam);
  hipLaunchKernelGGL(k_scan, dim3(B_ * R_), dim3(64), 0, stream,
                     z, lam, state, S, out + (size_t)B_ * T_ * D_);
  hipLaunchKernelGGL(k_phase3, dim3(B_ * T_ / G_), dim3(512), 0, stream,
                     x, g2, idx_m, wgd_m, V, S, f_ssm, fo_s, wq_m, fo_m, out);
}